// Round 8
// baseline (207.372 us; speedup 1.0000x reference)
//
#include <hip/hip_runtime.h>

#define V_CNT   10475
#define N3      31425      // V*3
#define NPAD    31488      // 164*192
#define J_CNT   55
#define NBETA   10
#define KP      512        // padded K for GEMM1 (486 pf + 10 betas + 1 vt + pad)
#define NFRAMES 512
#define BM      64         // frames per block
#define BNC     192        // columns (verts*3) per block
#define VTILES  164
#define FTILES  8

typedef __attribute__((ext_vector_type(8))) __bf16 bf16x8;
typedef __attribute__((ext_vector_type(8))) unsigned short ushort8;
typedef __attribute__((ext_vector_type(4))) float f32x4;

__device__ __forceinline__ unsigned short f2bf(float f) {
    unsigned u = __float_as_uint(f);
    u += 0x7fff + ((u >> 16) & 1);
    return (unsigned short)(u >> 16);
}
__device__ __forceinline__ float bf2f(unsigned short s) {
    return __uint_as_float(((unsigned)s) << 16);
}

__device__ __constant__ int c_parents[J_CNT] = {
    -1, 0, 0, 0, 1, 2, 3, 4, 5, 6, 7, 8, 9, 9, 9, 12, 13, 14, 16, 17, 18, 19,
    15, 15, 15,
    20, 25, 26, 20, 28, 29, 20, 31, 32, 20, 34, 35, 20, 37, 38,
    21, 40, 41, 21, 43, 44, 21, 46, 47, 21, 49, 50, 21, 52, 53};

// ---------------- skeleton: rotmats, kinematic chain, pf_ext(bf16), A_bf(bf16) ------------
__global__ __launch_bounds__(64) void skel_kernel(
    const float* __restrict__ body_pose, const float* __restrict__ betas,
    const float* __restrict__ global_orient, const float* __restrict__ J_template,
    const float* __restrict__ J_shapedirs, const float* __restrict__ odp,
    unsigned short* __restrict__ pf_ext, unsigned short* __restrict__ A_bf)
{
    const int n = blockIdx.x;
    const int lane = threadIdx.x;
    __shared__ float R_s[J_CNT][9];
    __shared__ float j_s[J_CNT][3];
    __shared__ float G_s[J_CNT][12];

    if (lane < J_CNT) {
        float aa0, aa1, aa2;
        if (lane == 0) {
            aa0 = global_orient[n * 3 + 0];
            aa1 = global_orient[n * 3 + 1];
            aa2 = global_orient[n * 3 + 2];
        } else if (lane < 22) {
            int o = n * 63 + (lane - 1) * 3;
            aa0 = body_pose[o]; aa1 = body_pose[o + 1]; aa2 = body_pose[o + 2];
        } else {
            int o = (lane - 22) * 3;
            aa0 = odp[o]; aa1 = odp[o + 1]; aa2 = odp[o + 2];
        }
        float ang = sqrtf(aa0 * aa0 + aa1 * aa1 + aa2 * aa2 + 1e-12f);
        float inv = 1.0f / ang;
        float ax = aa0 * inv, ay = aa1 * inv, az = aa2 * inv;
        float s = sinf(ang), c = cosf(ang), cc = 1.0f - c;
        float R[9];
        R[0] = c + cc * ax * ax;        R[1] = -s * az + cc * ax * ay;  R[2] = s * ay + cc * ax * az;
        R[3] = s * az + cc * ax * ay;   R[4] = c + cc * ay * ay;        R[5] = -s * ax + cc * ay * az;
        R[6] = -s * ay + cc * ax * az;  R[7] = s * ax + cc * ay * az;   R[8] = c + cc * az * az;
#pragma unroll
        for (int k = 0; k < 9; k++) R_s[lane][k] = R[k];
#pragma unroll
        for (int cd = 0; cd < 3; cd++) {
            float acc = J_template[lane * 3 + cd];
#pragma unroll
            for (int k = 0; k < NBETA; k++)
                acc += betas[n * NBETA + k] * J_shapedirs[(lane * 3 + cd) * NBETA + k];
            j_s[lane][cd] = acc;
        }
        if (lane >= 1) {
#pragma unroll
            for (int e = 0; e < 9; e++)
                pf_ext[n * KP + (lane - 1) * 9 + e] =
                    f2bf(R[e] - ((e == 0 || e == 4 || e == 8) ? 1.0f : 0.0f));
        }
    }
    if (lane == 55) {
#pragma unroll
        for (int b = 0; b < NBETA; b++) pf_ext[n * KP + 486 + b] = f2bf(betas[n * NBETA + b]);
        pf_ext[n * KP + 496] = 0x3F80;  // 1.0 bf16 (multiplies v_template row)
    }
    if (lane == 56) {
        for (int k = 497; k < KP; k++) pf_ext[n * KP + k] = 0;
    }
    __syncthreads();
    if (lane == 0) {
        for (int r = 0; r < 3; r++) {
            G_s[0][r * 4 + 0] = R_s[0][r * 3 + 0];
            G_s[0][r * 4 + 1] = R_s[0][r * 3 + 1];
            G_s[0][r * 4 + 2] = R_s[0][r * 3 + 2];
            G_s[0][r * 4 + 3] = j_s[0][r];
        }
        for (int i = 1; i < J_CNT; i++) {
            int p = c_parents[i];
            float rel0 = j_s[i][0] - j_s[p][0];
            float rel1 = j_s[i][1] - j_s[p][1];
            float rel2 = j_s[i][2] - j_s[p][2];
            for (int r = 0; r < 3; r++) {
                float g0 = G_s[p][r * 4 + 0], g1 = G_s[p][r * 4 + 1], g2 = G_s[p][r * 4 + 2];
                G_s[i][r * 4 + 0] = g0 * R_s[i][0] + g1 * R_s[i][3] + g2 * R_s[i][6];
                G_s[i][r * 4 + 1] = g0 * R_s[i][1] + g1 * R_s[i][4] + g2 * R_s[i][7];
                G_s[i][r * 4 + 2] = g0 * R_s[i][2] + g1 * R_s[i][5] + g2 * R_s[i][8];
                G_s[i][r * 4 + 3] = g0 * rel0 + g1 * rel1 + g2 * rel2 + G_s[p][r * 4 + 3];
            }
        }
    }
    __syncthreads();
    // A_bf[f][12][64]: row r = c*4+d of the 3x4 A matrix, K-dim = joint (padded to 64)
    float vals[12];
#pragma unroll
    for (int r = 0; r < 12; r++) vals[r] = 0.0f;
    if (lane < J_CNT) {
        const float jx = j_s[lane][0], jy = j_s[lane][1], jz = j_s[lane][2];
#pragma unroll
        for (int r = 0; r < 3; r++) {
            float g0 = G_s[lane][r * 4 + 0], g1 = G_s[lane][r * 4 + 1], g2 = G_s[lane][r * 4 + 2];
            vals[r * 4 + 0] = g0;
            vals[r * 4 + 1] = g1;
            vals[r * 4 + 2] = g2;
            vals[r * 4 + 3] = G_s[lane][r * 4 + 3] - (g0 * jx + g1 * jy + g2 * jz);
        }
    }
#pragma unroll
    for (int r = 0; r < 12; r++)
        A_bf[(n * 12 + r) * 64 + lane] = f2bf(vals[r]);
}

// ---------------- repack: B_pack[n][k] bf16 (transpose of posedirs, + shapedirs + v_template) ---
__global__ __launch_bounds__(256) void repack_kernel(
    const float* __restrict__ posedirs, const float* __restrict__ shapedirs,
    const float* __restrict__ v_template, unsigned short* __restrict__ B_pack)
{
    __shared__ float t[64][65];
    const int n0 = blockIdx.x * 64, k0 = blockIdx.y * 64;
    const int tn = threadIdx.x & 63, tk4 = threadIdx.x >> 6;
#pragma unroll
    for (int rep = 0; rep < 16; rep++) {
        int kl = rep * 4 + tk4;
        int kg = k0 + kl, ng = n0 + tn;
        float v = 0.0f;
        if (ng < N3) {
            if (kg < 486)       v = posedirs[(size_t)kg * N3 + ng];
            else if (kg < 496)  v = shapedirs[ng * NBETA + (kg - 486)];
            else if (kg == 496) v = v_template[ng];
        }
        t[kl][tn] = v;
    }
    __syncthreads();
    // store side: lane handles (n_local, kgroup of 8) -> one ushort8 (16B) store
#pragma unroll
    for (int rep = 0; rep < 2; rep++) {
        int nl = rep * 32 + (threadIdx.x >> 3);
        int kg = threadIdx.x & 7;
        ushort8 val;
#pragma unroll
        for (int j = 0; j < 8; j++) val[j] = f2bf(t[kg * 8 + j][nl]);
        *(ushort8*)(&B_pack[(size_t)(n0 + nl) * KP + k0 + kg * 8]) = val;
    }
}

// ---------------- fused GEMM: vposed -> skinning -> dense epilogue ------------------------
// block: 64 frames x 64 verts (192 cols). 4 waves as 2x2; wave tile 32f x 96c.
// GEMM1 reads BOTH operands directly global->VGPR (no LDS staging, no barriers):
// fragment lanes {i,i+16,i+32,i+48} read one contiguous 64B line of a 1KB-strided row,
// so loads are line-coalesced; pf_ext/A_bf are L2-resident, B_pack panels L2/L3-served.
__global__ __launch_bounds__(256, 3) void gemm_kernel(
    const unsigned short* __restrict__ pf_ext, const unsigned short* __restrict__ B_pack,
    const unsigned short* __restrict__ A_bf, const float* __restrict__ lbs_weights,
    const float* __restrict__ transl, float* __restrict__ out)
{
    // LDS map (34560 B total):
    //   0     w_b    8192      [64v][128B] = [64v][64j] bf16, XOR-swizzled chunks
    //   8192  tr_s   768       [64f][3] float
    //   8960  vp_s   25088     [64f][196] bf16       (overlaid by rst after GEMM2)
    //   8960  rst    25600     [32][200] float overlay (extends 512B past vp_s)
    __shared__ __align__(128) unsigned char smem[34560];
    unsigned char* w_b   = smem;
    float* tr_s          = (float*)(smem + 8192);
    unsigned short* vp_s = (unsigned short*)(smem + 8960);
    float* rst           = (float*)(smem + 8960);

    const int tid = threadIdx.x;
    const int w = tid >> 6, l = tid & 63;
    const int wm = w >> 1, wn = w & 1;         // wave tile: frames wm*32.., cols wn*96..
    const int f0 = blockIdx.y * BM;
    const int v00 = blockIdx.x * 64;
    const int n0c = blockIdx.x * BNC;

    // stage lbs weights tile -> w_b [64v][64j] bf16, XOR-swizzled chunks
    {
        int v = tid >> 2, jg = tid & 3;
        int vg = v00 + v;
#pragma unroll
        for (int h = 0; h < 2; h++) {
            ushort8 val;
#pragma unroll
            for (int e = 0; e < 8; e++) {
                int j = jg * 16 + h * 8 + e;
                float f = (vg < V_CNT && j < J_CNT) ? lbs_weights[vg * J_CNT + j] : 0.0f;
                val[e] = f2bf(f);
            }
            int chunk = (jg * 2 + h) ^ (v & 7);
            *(ushort8*)(w_b + v * 128 + chunk * 16) = val;
        }
    }
    if (tid < 192) tr_s[tid] = transl[f0 * 3 + tid];

    // -------- GEMM1: vp[f][n] = sum_k pf_ext[f][k] * B_pack[n][k], operands direct ---------
    f32x4 acc[2][6];
#pragma unroll
    for (int m = 0; m < 2; m++)
#pragma unroll
        for (int nn = 0; nn < 6; nn++) acc[m][nn] = (f32x4){0.f, 0.f, 0.f, 0.f};

    {
        // per-lane row bases (bytes); rows are KP*2 = 1024B
        const unsigned char* pA0 = (const unsigned char*)pf_ext +
                                   (size_t)(f0 + wm * 32 + (l & 15)) * 1024 + (l >> 4) * 16;
        const unsigned char* pB0 = (const unsigned char*)B_pack +
                                   (size_t)(n0c + wn * 96 + (l & 15)) * 1024 + (l >> 4) * 16;
#pragma unroll 4
        for (int kk = 0; kk < 16; kk++) {
            const int koff = kk * 64;
            bf16x8 a[2], b[6];
#pragma unroll
            for (int m = 0; m < 2; m++)
                a[m] = *(const bf16x8*)(pA0 + (size_t)m * 16 * 1024 + koff);
#pragma unroll
            for (int nn = 0; nn < 6; nn++)
                b[nn] = *(const bf16x8*)(pB0 + (size_t)nn * 16 * 1024 + koff);
#pragma unroll
            for (int m = 0; m < 2; m++)
#pragma unroll
                for (int nn = 0; nn < 6; nn++)
                    acc[m][nn] = __builtin_amdgcn_mfma_f32_16x16x32_bf16(a[m], b[nn], acc[m][nn], 0, 0, 0);
        }
    }

    // write vp to LDS as bf16 [64f][196] (dedicated region; no prior readers to wait on)
#pragma unroll
    for (int m = 0; m < 2; m++)
#pragma unroll
        for (int nn = 0; nn < 6; nn++)
#pragma unroll
            for (int e = 0; e < 4; e++) {
                int f = wm * 32 + m * 16 + (l >> 4) * 4 + e;
                int col = wn * 96 + nn * 16 + (l & 15);
                vp_s[f * 196 + col] = f2bf(acc[m][nn][e]);
            }
    __syncthreads();   // covers vp_s writes AND the w_b/tr_s staging at kernel start

    // -------- GEMM2 per coord c: T[f][v][c*4+rr] = sum_j A_bf[f][c*4+rr][j] * w[v][j] ------
    // c loop fully unrolled; res kept in registers (statically indexed).
    const unsigned char* Ab = (const unsigned char*)A_bf;
    float res[3][8][2];
#pragma unroll
    for (int c = 0; c < 3; c++) {
        f32x4 acc2[8][2];
#pragma unroll
        for (int m = 0; m < 8; m++)
#pragma unroll
            for (int nn = 0; nn < 2; nn++) acc2[m][nn] = (f32x4){0.f, 0.f, 0.f, 0.f};
#pragma unroll
        for (int ksub = 0; ksub < 2; ksub++) {
            bf16x8 bw[2];
#pragma unroll
            for (int nn = 0; nn < 2; nn++) {
                int v = wn * 32 + nn * 16 + (l & 15);
                int off = v * 128 + ((ksub * 64 + (l >> 4) * 16) ^ ((v & 7) << 4));
                bw[nn] = *(const bf16x8*)(w_b + off);
            }
#pragma unroll
            for (int m = 0; m < 8; m++) {
                int row16 = l & 15;
                int f_rel = m * 4 + (row16 >> 2);
                int rr = row16 & 3;
                const unsigned char* asrc = Ab +
                    ((size_t)((f0 + wm * 32 + f_rel) * 12 + c * 4 + rr)) * 128 +
                    ksub * 64 + (l >> 4) * 16;
                bf16x8 af = *(const bf16x8*)asrc;
                acc2[m][0] = __builtin_amdgcn_mfma_f32_16x16x32_bf16(af, bw[0], acc2[m][0], 0, 0, 0);
                acc2[m][1] = __builtin_amdgcn_mfma_f32_16x16x32_bf16(af, bw[1], acc2[m][1], 0, 0, 0);
            }
        }
#pragma unroll
        for (int m = 0; m < 8; m++)
#pragma unroll
            for (int nn = 0; nn < 2; nn++) {
                int f_rel = wm * 32 + m * 4 + (l >> 4);      // frame within block
                int vloc = wn * 32 + nn * 16 + (l & 15);     // vertex within block
                float d0 = bf2f(vp_s[f_rel * 196 + vloc * 3 + 0]);
                float d1 = bf2f(vp_s[f_rel * 196 + vloc * 3 + 1]);
                float d2 = bf2f(vp_s[f_rel * 196 + vloc * 3 + 2]);
                f32x4 tt = acc2[m][nn];
                res[c][m][nn] = tt[0] * d0 + tt[1] * d1 + tt[2] * d2 + tt[3] + tr_s[f_rel * 3 + c];
            }
    }

    // -------- dense epilogue: restage res through LDS, write lane-consecutive dwords ------
    // rst[32][200] floats overlays vp_s (all vp_s reads completed above).
    const int olim = N3 - v00 * 3;   // valid dwords within a 192-dword row (tail block)
#pragma unroll
    for (int chunk = 0; chunk < 2; chunk++) {
        __syncthreads();   // all vp_s reads done (chunk 0) / prior copy done (chunk 1)
        if (wm == chunk) {
#pragma unroll
            for (int m = 0; m < 8; m++)
#pragma unroll
                for (int nn = 0; nn < 2; nn++) {
                    int r = m * 4 + (l >> 4);
                    int colv = (wn * 32 + nn * 16 + (l & 15)) * 3;
#pragma unroll
                    for (int c = 0; c < 3; c++)
                        rst[r * 200 + colv + c] = res[c][m][nn];
                }
        }
        __syncthreads();
        size_t base = ((size_t)(f0 + chunk * 32) * V_CNT + v00) * 3;
#pragma unroll
        for (int k = 0; k < 24; k++) {
            int i = tid + k * 256;
            int r = i / 192;
            int o = i - r * 192;
            if (o < olim)
                out[base + (size_t)r * N3 + o] = rst[r * 200 + o];
        }
    }
}

extern "C" void kernel_launch(void* const* d_in, const int* in_sizes, int n_in,
                              void* d_out, int out_size, void* d_ws, size_t ws_size,
                              hipStream_t stream)
{
    const float* body_pose     = (const float*)d_in[0];
    const float* betas         = (const float*)d_in[1];
    const float* global_orient = (const float*)d_in[2];
    const float* transl        = (const float*)d_in[3];
    const float* v_template    = (const float*)d_in[4];
    const float* shapedirs     = (const float*)d_in[5];
    const float* posedirs      = (const float*)d_in[6];
    const float* lbs_weights   = (const float*)d_in[7];
    const float* J_template    = (const float*)d_in[8];
    const float* J_shapedirs   = (const float*)d_in[9];
    const float* odp           = (const float*)d_in[10];
    float* out = (float*)d_out;

    // ws layout: B_pack 31488*512*2 = 32,243,712 | pf_ext 512*512*2 | A_bf 512*12*64*2
    unsigned short* B_pack = (unsigned short*)d_ws;
    unsigned short* pf_ext = (unsigned short*)((char*)d_ws + 32243712);
    unsigned short* A_bf   = (unsigned short*)((char*)d_ws + 32243712 + 524288);

    dim3 rgrid(NPAD / 64, KP / 64);
    repack_kernel<<<rgrid, 256, 0, stream>>>(posedirs, shapedirs, v_template, B_pack);

    skel_kernel<<<NFRAMES, 64, 0, stream>>>(body_pose, betas, global_orient,
                                            J_template, J_shapedirs, odp,
                                            pf_ext, A_bf);

    dim3 ggrid(VTILES, FTILES);
    gemm_kernel<<<ggrid, 256, 0, stream>>>(pf_ext, B_pack, A_bf, lbs_weights, transl, out);
}

// Round 9
// 195.220 us; speedup vs baseline: 1.0622x; 1.0622x over previous
//
#include <hip/hip_runtime.h>

#define V_CNT   10475
#define N3      31425      // V*3
#define NPAD    31488      // 164*192
#define J_CNT   55
#define NBETA   10
#define KP      512        // padded K for GEMM1 (486 pf + 10 betas + 1 vt + pad)
#define NFRAMES 512
#define BM      64         // frames per block
#define BNC     192        // columns (verts*3) per block
#define VTILES  164
#define FTILES  8

typedef __attribute__((ext_vector_type(8))) __bf16 bf16x8;
typedef __attribute__((ext_vector_type(8))) unsigned short ushort8;
typedef __attribute__((ext_vector_type(4))) float f32x4;

__device__ __forceinline__ unsigned short f2bf(float f) {
    unsigned u = __float_as_uint(f);
    u += 0x7fff + ((u >> 16) & 1);
    return (unsigned short)(u >> 16);
}
__device__ __forceinline__ float bf2f(unsigned short s) {
    return __uint_as_float(((unsigned)s) << 16);
}

__device__ __constant__ int c_parents[J_CNT] = {
    -1, 0, 0, 0, 1, 2, 3, 4, 5, 6, 7, 8, 9, 9, 9, 12, 13, 14, 16, 17, 18, 19,
    15, 15, 15,
    20, 25, 26, 20, 28, 29, 20, 31, 32, 20, 34, 35, 20, 37, 38,
    21, 40, 41, 21, 43, 44, 21, 46, 47, 21, 49, 50, 21, 52, 53};

// ---------------- skeleton: rotmats, kinematic chain, pf_ext(bf16), A_bf(bf16) ------------
__global__ __launch_bounds__(64) void skel_kernel(
    const float* __restrict__ body_pose, const float* __restrict__ betas,
    const float* __restrict__ global_orient, const float* __restrict__ J_template,
    const float* __restrict__ J_shapedirs, const float* __restrict__ odp,
    unsigned short* __restrict__ pf_ext, unsigned short* __restrict__ A_bf)
{
    const int n = blockIdx.x;
    const int lane = threadIdx.x;
    __shared__ float R_s[J_CNT][9];
    __shared__ float j_s[J_CNT][3];
    __shared__ float G_s[J_CNT][12];

    if (lane < J_CNT) {
        float aa0, aa1, aa2;
        if (lane == 0) {
            aa0 = global_orient[n * 3 + 0];
            aa1 = global_orient[n * 3 + 1];
            aa2 = global_orient[n * 3 + 2];
        } else if (lane < 22) {
            int o = n * 63 + (lane - 1) * 3;
            aa0 = body_pose[o]; aa1 = body_pose[o + 1]; aa2 = body_pose[o + 2];
        } else {
            int o = (lane - 22) * 3;
            aa0 = odp[o]; aa1 = odp[o + 1]; aa2 = odp[o + 2];
        }
        float ang = sqrtf(aa0 * aa0 + aa1 * aa1 + aa2 * aa2 + 1e-12f);
        float inv = 1.0f / ang;
        float ax = aa0 * inv, ay = aa1 * inv, az = aa2 * inv;
        float s = sinf(ang), c = cosf(ang), cc = 1.0f - c;
        float R[9];
        R[0] = c + cc * ax * ax;        R[1] = -s * az + cc * ax * ay;  R[2] = s * ay + cc * ax * az;
        R[3] = s * az + cc * ax * ay;   R[4] = c + cc * ay * ay;        R[5] = -s * ax + cc * ay * az;
        R[6] = -s * ay + cc * ax * az;  R[7] = s * ax + cc * ay * az;   R[8] = c + cc * az * az;
#pragma unroll
        for (int k = 0; k < 9; k++) R_s[lane][k] = R[k];
#pragma unroll
        for (int cd = 0; cd < 3; cd++) {
            float acc = J_template[lane * 3 + cd];
#pragma unroll
            for (int k = 0; k < NBETA; k++)
                acc += betas[n * NBETA + k] * J_shapedirs[(lane * 3 + cd) * NBETA + k];
            j_s[lane][cd] = acc;
        }
        if (lane >= 1) {
#pragma unroll
            for (int e = 0; e < 9; e++)
                pf_ext[n * KP + (lane - 1) * 9 + e] =
                    f2bf(R[e] - ((e == 0 || e == 4 || e == 8) ? 1.0f : 0.0f));
        }
    }
    if (lane == 55) {
#pragma unroll
        for (int b = 0; b < NBETA; b++) pf_ext[n * KP + 486 + b] = f2bf(betas[n * NBETA + b]);
        pf_ext[n * KP + 496] = 0x3F80;  // 1.0 bf16 (multiplies v_template row)
    }
    if (lane == 56) {
        for (int k = 497; k < KP; k++) pf_ext[n * KP + k] = 0;
    }
    __syncthreads();
    if (lane == 0) {
        for (int r = 0; r < 3; r++) {
            G_s[0][r * 4 + 0] = R_s[0][r * 3 + 0];
            G_s[0][r * 4 + 1] = R_s[0][r * 3 + 1];
            G_s[0][r * 4 + 2] = R_s[0][r * 3 + 2];
            G_s[0][r * 4 + 3] = j_s[0][r];
        }
        for (int i = 1; i < J_CNT; i++) {
            int p = c_parents[i];
            float rel0 = j_s[i][0] - j_s[p][0];
            float rel1 = j_s[i][1] - j_s[p][1];
            float rel2 = j_s[i][2] - j_s[p][2];
            for (int r = 0; r < 3; r++) {
                float g0 = G_s[p][r * 4 + 0], g1 = G_s[p][r * 4 + 1], g2 = G_s[p][r * 4 + 2];
                G_s[i][r * 4 + 0] = g0 * R_s[i][0] + g1 * R_s[i][3] + g2 * R_s[i][6];
                G_s[i][r * 4 + 1] = g0 * R_s[i][1] + g1 * R_s[i][4] + g2 * R_s[i][7];
                G_s[i][r * 4 + 2] = g0 * R_s[i][2] + g1 * R_s[i][5] + g2 * R_s[i][8];
                G_s[i][r * 4 + 3] = g0 * rel0 + g1 * rel1 + g2 * rel2 + G_s[p][r * 4 + 3];
            }
        }
    }
    __syncthreads();
    // A_bf[f][12][64]: row r = c*4+d of the 3x4 A matrix, K-dim = joint (padded to 64)
    float vals[12];
#pragma unroll
    for (int r = 0; r < 12; r++) vals[r] = 0.0f;
    if (lane < J_CNT) {
        const float jx = j_s[lane][0], jy = j_s[lane][1], jz = j_s[lane][2];
#pragma unroll
        for (int r = 0; r < 3; r++) {
            float g0 = G_s[lane][r * 4 + 0], g1 = G_s[lane][r * 4 + 1], g2 = G_s[lane][r * 4 + 2];
            vals[r * 4 + 0] = g0;
            vals[r * 4 + 1] = g1;
            vals[r * 4 + 2] = g2;
            vals[r * 4 + 3] = G_s[lane][r * 4 + 3] - (g0 * jx + g1 * jy + g2 * jz);
        }
    }
#pragma unroll
    for (int r = 0; r < 12; r++)
        A_bf[(n * 12 + r) * 64 + lane] = f2bf(vals[r]);
}

// ---------------- repack: B_pack[n][k] bf16 (transpose of posedirs, + shapedirs + v_template) ---
__global__ __launch_bounds__(256) void repack_kernel(
    const float* __restrict__ posedirs, const float* __restrict__ shapedirs,
    const float* __restrict__ v_template, unsigned short* __restrict__ B_pack)
{
    __shared__ float t[64][65];
    const int n0 = blockIdx.x * 64, k0 = blockIdx.y * 64;
    const int tn = threadIdx.x & 63, tk4 = threadIdx.x >> 6;
#pragma unroll
    for (int rep = 0; rep < 16; rep++) {
        int kl = rep * 4 + tk4;
        int kg = k0 + kl, ng = n0 + tn;
        float v = 0.0f;
        if (ng < N3) {
            if (kg < 486)       v = posedirs[(size_t)kg * N3 + ng];
            else if (kg < 496)  v = shapedirs[ng * NBETA + (kg - 486)];
            else if (kg == 496) v = v_template[ng];
        }
        t[kl][tn] = v;
    }
    __syncthreads();
    // store side: lane handles (n_local, kgroup of 8) -> one ushort8 (16B) store
#pragma unroll
    for (int rep = 0; rep < 2; rep++) {
        int nl = rep * 32 + (threadIdx.x >> 3);
        int kg = threadIdx.x & 7;
        ushort8 val;
#pragma unroll
        for (int j = 0; j < 8; j++) val[j] = f2bf(t[kg * 8 + j][nl]);
        *(ushort8*)(&B_pack[(size_t)(n0 + nl) * KP + k0 + kg * 8]) = val;
    }
}

// ---------------- fused GEMM: vposed -> skinning -> dense epilogue ------------------------
// block: 64 frames x 64 verts (192 cols). 4 waves as 2x2; wave tile 32f x 96c.
// GEMM1 reads BOTH operands directly global->VGPR (no LDS staging, no barriers).
// launch_bounds (256,2): VGPR cap 256. (256,3) capped at 84 and spilled res[] to
// scratch (R4 AND R8 counters — ~88MB each way). Never tighten the cap on a
// VGPR-hungry structure.
__global__ __launch_bounds__(256, 2) void gemm_kernel(
    const unsigned short* __restrict__ pf_ext, const unsigned short* __restrict__ B_pack,
    const unsigned short* __restrict__ A_bf, const float* __restrict__ lbs_weights,
    const float* __restrict__ transl, float* __restrict__ out)
{
    // LDS map (34560 B total):
    //   0     w_b    8192      [64v][128B] = [64v][64j] bf16, XOR-swizzled chunks
    //   8192  tr_s   768       [64f][3] float
    //   8960  vp_s   25088     [64f][196] bf16       (overlaid by rst after GEMM2)
    //   8960  rst    25600     [32][200] float overlay (extends 512B past vp_s)
    __shared__ __align__(128) unsigned char smem[34560];
    unsigned char* w_b   = smem;
    float* tr_s          = (float*)(smem + 8192);
    unsigned short* vp_s = (unsigned short*)(smem + 8960);
    float* rst           = (float*)(smem + 8960);

    const int tid = threadIdx.x;
    const int w = tid >> 6, l = tid & 63;
    const int wm = w >> 1, wn = w & 1;         // wave tile: frames wm*32.., cols wn*96..
    const int f0 = blockIdx.y * BM;
    const int v00 = blockIdx.x * 64;
    const int n0c = blockIdx.x * BNC;

    // stage lbs weights tile -> w_b [64v][64j] bf16, XOR-swizzled chunks
    {
        int v = tid >> 2, jg = tid & 3;
        int vg = v00 + v;
#pragma unroll
        for (int h = 0; h < 2; h++) {
            ushort8 val;
#pragma unroll
            for (int e = 0; e < 8; e++) {
                int j = jg * 16 + h * 8 + e;
                float f = (vg < V_CNT && j < J_CNT) ? lbs_weights[vg * J_CNT + j] : 0.0f;
                val[e] = f2bf(f);
            }
            int chunk = (jg * 2 + h) ^ (v & 7);
            *(ushort8*)(w_b + v * 128 + chunk * 16) = val;
        }
    }
    if (tid < 192) tr_s[tid] = transl[f0 * 3 + tid];

    // -------- GEMM1: vp[f][n] = sum_k pf_ext[f][k] * B_pack[n][k], operands direct ---------
    f32x4 acc[2][6];
#pragma unroll
    for (int m = 0; m < 2; m++)
#pragma unroll
        for (int nn = 0; nn < 6; nn++) acc[m][nn] = (f32x4){0.f, 0.f, 0.f, 0.f};

    {
        // per-lane row bases (bytes); rows are KP*2 = 1024B
        const unsigned char* pA0 = (const unsigned char*)pf_ext +
                                   (size_t)(f0 + wm * 32 + (l & 15)) * 1024 + (l >> 4) * 16;
        const unsigned char* pB0 = (const unsigned char*)B_pack +
                                   (size_t)(n0c + wn * 96 + (l & 15)) * 1024 + (l >> 4) * 16;
#pragma unroll 4
        for (int kk = 0; kk < 16; kk++) {
            const int koff = kk * 64;
            bf16x8 a[2], b[6];
#pragma unroll
            for (int m = 0; m < 2; m++)
                a[m] = *(const bf16x8*)(pA0 + (size_t)m * 16 * 1024 + koff);
#pragma unroll
            for (int nn = 0; nn < 6; nn++)
                b[nn] = *(const bf16x8*)(pB0 + (size_t)nn * 16 * 1024 + koff);
#pragma unroll
            for (int m = 0; m < 2; m++)
#pragma unroll
                for (int nn = 0; nn < 6; nn++)
                    acc[m][nn] = __builtin_amdgcn_mfma_f32_16x16x32_bf16(a[m], b[nn], acc[m][nn], 0, 0, 0);
        }
    }

    // write vp to LDS as bf16 [64f][196] (dedicated region; no prior readers to wait on)
#pragma unroll
    for (int m = 0; m < 2; m++)
#pragma unroll
        for (int nn = 0; nn < 6; nn++)
#pragma unroll
            for (int e = 0; e < 4; e++) {
                int f = wm * 32 + m * 16 + (l >> 4) * 4 + e;
                int col = wn * 96 + nn * 16 + (l & 15);
                vp_s[f * 196 + col] = f2bf(acc[m][nn][e]);
            }
    __syncthreads();   // covers vp_s writes AND the w_b/tr_s staging at kernel start

    // -------- GEMM2 per coord c: T[f][v][c*4+rr] = sum_j A_bf[f][c*4+rr][j] * w[v][j] ------
    // c loop fully unrolled; res kept in registers (statically indexed).
    const unsigned char* Ab = (const unsigned char*)A_bf;
    float res[3][8][2];
#pragma unroll
    for (int c = 0; c < 3; c++) {
        f32x4 acc2[8][2];
#pragma unroll
        for (int m = 0; m < 8; m++)
#pragma unroll
            for (int nn = 0; nn < 2; nn++) acc2[m][nn] = (f32x4){0.f, 0.f, 0.f, 0.f};
#pragma unroll
        for (int ksub = 0; ksub < 2; ksub++) {
            bf16x8 bw[2];
#pragma unroll
            for (int nn = 0; nn < 2; nn++) {
                int v = wn * 32 + nn * 16 + (l & 15);
                int off = v * 128 + ((ksub * 64 + (l >> 4) * 16) ^ ((v & 7) << 4));
                bw[nn] = *(const bf16x8*)(w_b + off);
            }
#pragma unroll
            for (int m = 0; m < 8; m++) {
                int row16 = l & 15;
                int f_rel = m * 4 + (row16 >> 2);
                int rr = row16 & 3;
                const unsigned char* asrc = Ab +
                    ((size_t)((f0 + wm * 32 + f_rel) * 12 + c * 4 + rr)) * 128 +
                    ksub * 64 + (l >> 4) * 16;
                bf16x8 af = *(const bf16x8*)asrc;
                acc2[m][0] = __builtin_amdgcn_mfma_f32_16x16x32_bf16(af, bw[0], acc2[m][0], 0, 0, 0);
                acc2[m][1] = __builtin_amdgcn_mfma_f32_16x16x32_bf16(af, bw[1], acc2[m][1], 0, 0, 0);
            }
        }
#pragma unroll
        for (int m = 0; m < 8; m++)
#pragma unroll
            for (int nn = 0; nn < 2; nn++) {
                int f_rel = wm * 32 + m * 4 + (l >> 4);      // frame within block
                int vloc = wn * 32 + nn * 16 + (l & 15);     // vertex within block
                float d0 = bf2f(vp_s[f_rel * 196 + vloc * 3 + 0]);
                float d1 = bf2f(vp_s[f_rel * 196 + vloc * 3 + 1]);
                float d2 = bf2f(vp_s[f_rel * 196 + vloc * 3 + 2]);
                f32x4 tt = acc2[m][nn];
                res[c][m][nn] = tt[0] * d0 + tt[1] * d1 + tt[2] * d2 + tt[3] + tr_s[f_rel * 3 + c];
            }
    }

    // -------- dense epilogue: restage res through LDS, write lane-consecutive dwords ------
    // rst[32][200] floats overlays vp_s (all vp_s reads completed above).
    const int olim = N3 - v00 * 3;   // valid dwords within a 192-dword row (tail block)
#pragma unroll
    for (int chunk = 0; chunk < 2; chunk++) {
        __syncthreads();   // all vp_s reads done (chunk 0) / prior copy done (chunk 1)
        if (wm == chunk) {
#pragma unroll
            for (int m = 0; m < 8; m++)
#pragma unroll
                for (int nn = 0; nn < 2; nn++) {
                    int r = m * 4 + (l >> 4);
                    int colv = (wn * 32 + nn * 16 + (l & 15)) * 3;
#pragma unroll
                    for (int c = 0; c < 3; c++)
                        rst[r * 200 + colv + c] = res[c][m][nn];
                }
        }
        __syncthreads();
        size_t base = ((size_t)(f0 + chunk * 32) * V_CNT + v00) * 3;
#pragma unroll
        for (int k = 0; k < 24; k++) {
            int i = tid + k * 256;
            int r = i / 192;
            int o = i - r * 192;
            if (o < olim)
                out[base + (size_t)r * N3 + o] = rst[r * 200 + o];
        }
    }
}

extern "C" void kernel_launch(void* const* d_in, const int* in_sizes, int n_in,
                              void* d_out, int out_size, void* d_ws, size_t ws_size,
                              hipStream_t stream)
{
    const float* body_pose     = (const float*)d_in[0];
    const float* betas         = (const float*)d_in[1];
    const float* global_orient = (const float*)d_in[2];
    const float* transl        = (const float*)d_in[3];
    const float* v_template    = (const float*)d_in[4];
    const float* shapedirs     = (const float*)d_in[5];
    const float* posedirs      = (const float*)d_in[6];
    const float* lbs_weights   = (const float*)d_in[7];
    const float* J_template    = (const float*)d_in[8];
    const float* J_shapedirs   = (const float*)d_in[9];
    const float* odp           = (const float*)d_in[10];
    float* out = (float*)d_out;

    // ws layout: B_pack 31488*512*2 = 32,243,712 | pf_ext 512*512*2 | A_bf 512*12*64*2
    unsigned short* B_pack = (unsigned short*)d_ws;
    unsigned short* pf_ext = (unsigned short*)((char*)d_ws + 32243712);
    unsigned short* A_bf   = (unsigned short*)((char*)d_ws + 32243712 + 524288);

    dim3 rgrid(NPAD / 64, KP / 64);
    repack_kernel<<<rgrid, 256, 0, stream>>>(posedirs, shapedirs, v_template, B_pack);

    skel_kernel<<<NFRAMES, 64, 0, stream>>>(body_pose, betas, global_orient,
                                            J_template, J_shapedirs, odp,
                                            pf_ext, A_bf);

    dim3 ggrid(VTILES, FTILES);
    gemm_kernel<<<ggrid, 256, 0, stream>>>(pf_ext, B_pack, A_bf, lbs_weights, transl, out);
}

// Round 10
// 119.044 us; speedup vs baseline: 1.7420x; 1.6399x over previous
//
#include <hip/hip_runtime.h>

#define V_CNT   10475
#define N3      31425      // V*3
#define NPAD    31488      // 164*192
#define J_CNT   55
#define NBETA   10
#define KP      512        // padded K for GEMM1 (486 pf + 10 betas + 1 vt + pad)
#define NFRAMES 512
#define BM      64         // frames per block
#define BNC     192        // columns (verts*3) per block
#define VTILES  164
#define FTILES  8

typedef __attribute__((ext_vector_type(8))) __bf16 bf16x8;
typedef __attribute__((ext_vector_type(8))) unsigned short ushort8;
typedef __attribute__((ext_vector_type(4))) float f32x4;

__device__ __forceinline__ unsigned short f2bf(float f) {
    unsigned u = __float_as_uint(f);
    u += 0x7fff + ((u >> 16) & 1);
    return (unsigned short)(u >> 16);
}
__device__ __forceinline__ float bf2f(unsigned short s) {
    return __uint_as_float(((unsigned)s) << 16);
}
// global -> LDS direct 16B load. LDS dest must be wave-uniform; lane writes base+lane*16.
__device__ __forceinline__ void gl_lds16(const void* g, void* l) {
    auto gp = (const __attribute__((address_space(1))) unsigned int*)(uintptr_t)g;
    auto lp = (__attribute__((address_space(3))) unsigned int*)(unsigned int)(uintptr_t)l;
    __builtin_amdgcn_global_load_lds(gp, lp, 16, 0, 0);
}

__device__ __constant__ int c_parents[J_CNT] = {
    -1, 0, 0, 0, 1, 2, 3, 4, 5, 6, 7, 8, 9, 9, 9, 12, 13, 14, 16, 17, 18, 19,
    15, 15, 15,
    20, 25, 26, 20, 28, 29, 20, 31, 32, 20, 34, 35, 20, 37, 38,
    21, 40, 41, 21, 43, 44, 21, 46, 47, 21, 49, 50, 21, 52, 53};

// ---------------- skeleton: rotmats, kinematic chain, pf_ext(bf16), A_bf(bf16) ------------
__global__ __launch_bounds__(64) void skel_kernel(
    const float* __restrict__ body_pose, const float* __restrict__ betas,
    const float* __restrict__ global_orient, const float* __restrict__ J_template,
    const float* __restrict__ J_shapedirs, const float* __restrict__ odp,
    unsigned short* __restrict__ pf_ext, unsigned short* __restrict__ A_bf)
{
    const int n = blockIdx.x;
    const int lane = threadIdx.x;
    __shared__ float R_s[J_CNT][9];
    __shared__ float j_s[J_CNT][3];
    __shared__ float G_s[J_CNT][12];

    if (lane < J_CNT) {
        float aa0, aa1, aa2;
        if (lane == 0) {
            aa0 = global_orient[n * 3 + 0];
            aa1 = global_orient[n * 3 + 1];
            aa2 = global_orient[n * 3 + 2];
        } else if (lane < 22) {
            int o = n * 63 + (lane - 1) * 3;
            aa0 = body_pose[o]; aa1 = body_pose[o + 1]; aa2 = body_pose[o + 2];
        } else {
            int o = (lane - 22) * 3;
            aa0 = odp[o]; aa1 = odp[o + 1]; aa2 = odp[o + 2];
        }
        float ang = sqrtf(aa0 * aa0 + aa1 * aa1 + aa2 * aa2 + 1e-12f);
        float inv = 1.0f / ang;
        float ax = aa0 * inv, ay = aa1 * inv, az = aa2 * inv;
        float s = sinf(ang), c = cosf(ang), cc = 1.0f - c;
        float R[9];
        R[0] = c + cc * ax * ax;        R[1] = -s * az + cc * ax * ay;  R[2] = s * ay + cc * ax * az;
        R[3] = s * az + cc * ax * ay;   R[4] = c + cc * ay * ay;        R[5] = -s * ax + cc * ay * az;
        R[6] = -s * ay + cc * ax * az;  R[7] = s * ax + cc * ay * az;   R[8] = c + cc * az * az;
#pragma unroll
        for (int k = 0; k < 9; k++) R_s[lane][k] = R[k];
#pragma unroll
        for (int cd = 0; cd < 3; cd++) {
            float acc = J_template[lane * 3 + cd];
#pragma unroll
            for (int k = 0; k < NBETA; k++)
                acc += betas[n * NBETA + k] * J_shapedirs[(lane * 3 + cd) * NBETA + k];
            j_s[lane][cd] = acc;
        }
        if (lane >= 1) {
#pragma unroll
            for (int e = 0; e < 9; e++)
                pf_ext[n * KP + (lane - 1) * 9 + e] =
                    f2bf(R[e] - ((e == 0 || e == 4 || e == 8) ? 1.0f : 0.0f));
        }
    }
    if (lane == 55) {
#pragma unroll
        for (int b = 0; b < NBETA; b++) pf_ext[n * KP + 486 + b] = f2bf(betas[n * NBETA + b]);
        pf_ext[n * KP + 496] = 0x3F80;  // 1.0 bf16 (multiplies v_template row)
    }
    if (lane == 56) {
        for (int k = 497; k < KP; k++) pf_ext[n * KP + k] = 0;
    }
    __syncthreads();
    if (lane == 0) {
        for (int r = 0; r < 3; r++) {
            G_s[0][r * 4 + 0] = R_s[0][r * 3 + 0];
            G_s[0][r * 4 + 1] = R_s[0][r * 3 + 1];
            G_s[0][r * 4 + 2] = R_s[0][r * 3 + 2];
            G_s[0][r * 4 + 3] = j_s[0][r];
        }
        for (int i = 1; i < J_CNT; i++) {
            int p = c_parents[i];
            float rel0 = j_s[i][0] - j_s[p][0];
            float rel1 = j_s[i][1] - j_s[p][1];
            float rel2 = j_s[i][2] - j_s[p][2];
            for (int r = 0; r < 3; r++) {
                float g0 = G_s[p][r * 4 + 0], g1 = G_s[p][r * 4 + 1], g2 = G_s[p][r * 4 + 2];
                G_s[i][r * 4 + 0] = g0 * R_s[i][0] + g1 * R_s[i][3] + g2 * R_s[i][6];
                G_s[i][r * 4 + 1] = g0 * R_s[i][1] + g1 * R_s[i][4] + g2 * R_s[i][7];
                G_s[i][r * 4 + 2] = g0 * R_s[i][2] + g1 * R_s[i][5] + g2 * R_s[i][8];
                G_s[i][r * 4 + 3] = g0 * rel0 + g1 * rel1 + g2 * rel2 + G_s[p][r * 4 + 3];
            }
        }
    }
    __syncthreads();
    // A_bf[f][12][64]: row r = c*4+d of the 3x4 A matrix, K-dim = joint (padded to 64)
    float vals[12];
#pragma unroll
    for (int r = 0; r < 12; r++) vals[r] = 0.0f;
    if (lane < J_CNT) {
        const float jx = j_s[lane][0], jy = j_s[lane][1], jz = j_s[lane][2];
#pragma unroll
        for (int r = 0; r < 3; r++) {
            float g0 = G_s[lane][r * 4 + 0], g1 = G_s[lane][r * 4 + 1], g2 = G_s[lane][r * 4 + 2];
            vals[r * 4 + 0] = g0;
            vals[r * 4 + 1] = g1;
            vals[r * 4 + 2] = g2;
            vals[r * 4 + 3] = G_s[lane][r * 4 + 3] - (g0 * jx + g1 * jy + g2 * jz);
        }
    }
#pragma unroll
    for (int r = 0; r < 12; r++)
        A_bf[(n * 12 + r) * 64 + lane] = f2bf(vals[r]);
}

// ---------------- repack: B_pack[n][k] bf16 (transpose of posedirs, + shapedirs + v_template) ---
__global__ __launch_bounds__(256) void repack_kernel(
    const float* __restrict__ posedirs, const float* __restrict__ shapedirs,
    const float* __restrict__ v_template, unsigned short* __restrict__ B_pack)
{
    __shared__ float t[64][65];
    const int n0 = blockIdx.x * 64, k0 = blockIdx.y * 64;
    const int tn = threadIdx.x & 63, tk4 = threadIdx.x >> 6;
#pragma unroll
    for (int rep = 0; rep < 16; rep++) {
        int kl = rep * 4 + tk4;
        int kg = k0 + kl, ng = n0 + tn;
        float v = 0.0f;
        if (ng < N3) {
            if (kg < 486)       v = posedirs[(size_t)kg * N3 + ng];
            else if (kg < 496)  v = shapedirs[ng * NBETA + (kg - 486)];
            else if (kg == 496) v = v_template[ng];
        }
        t[kl][tn] = v;
    }
    __syncthreads();
    // store side: lane handles (n_local, kgroup of 8) -> one ushort8 (16B) store
#pragma unroll
    for (int rep = 0; rep < 2; rep++) {
        int nl = rep * 32 + (threadIdx.x >> 3);
        int kg = threadIdx.x & 7;
        ushort8 val;
#pragma unroll
        for (int j = 0; j < 8; j++) val[j] = f2bf(t[kg * 8 + j][nl]);
        *(ushort8*)(&B_pack[(size_t)(n0 + nl) * KP + k0 + kg * 8]) = val;
    }
}

// ---------------- fused GEMM: vposed (MFMA, 2-phase dbuf pipeline) -> skinning -> epilogue --
// R7 structure + XCD co-location swizzle: all 8 frame-tiles of a vtile map to the same
// bid%8 (same XCD, adjacent dispatch) so the shared 192KB B panel stays L2-resident.
__global__ __launch_bounds__(256, 2) void gemm_kernel(
    const unsigned short* __restrict__ pf_ext, const unsigned short* __restrict__ B_pack,
    const unsigned short* __restrict__ A_bf, const float* __restrict__ lbs_weights,
    const float* __restrict__ transl, float* __restrict__ out)
{
    // LDS map (74496 B total -> 2 blocks/CU):
    //   0     pf_b[0] 8192      [64f][128B] swizzled
    //   8192  pf_b[1] 8192
    //   16384 B_b[0] 24576      [192n][128B] swizzled
    //   40960 B_b[1] 24576
    //   65536 w_b    8192       [64v][128B] swizzled
    //   73728 tr_s   768
    // overlays (after GEMM1 completes):
    //   vp_s  = smem+16384, [64f][196] ushort
    //   rst   = smem+41472, [32][200] float
    __shared__ __align__(128) unsigned char smem[74496];
    unsigned char* pf_b0 = smem;
    unsigned char* pf_b1 = smem + 8192;
    unsigned char* B_b0  = smem + 16384;
    unsigned char* B_b1  = smem + 40960;
    unsigned char* w_b   = smem + 65536;
    float* tr_s          = (float*)(smem + 73728);
    unsigned short* vp_s = (unsigned short*)(smem + 16384);
    float* rst           = (float*)(smem + 41472);

    const int tid = threadIdx.x;
    const int w = tid >> 6, l = tid & 63;
    const int wm = w >> 1, wn = w & 1;         // wave tile: frames wm*32.., cols wn*96..

    // ---- XCD co-location decode: 64-block groups = 8 vtiles x 8 ftiles; within a group
    // vtile = gi&7 = bid%8 -> XCD (round-robin), so a vtile's 8 ftile-blocks share an XCD.
    const int bid = blockIdx.x;
    const int group = bid >> 6, gi = bid & 63;
    int vt, ft;
    if (group < 20) { vt = group * 8 + (gi & 7); ft = gi >> 3; }
    else            { vt = 160 + (gi & 3);       ft = gi >> 2; }   // tail: 4 vtiles
    const int f0 = ft * BM;
    const int v00 = vt * 64;
    const int n0c = vt * BNC;

    // stage lbs weights tile -> w_b [64v][64j] bf16, XOR-swizzled chunks
    {
        int v = tid >> 2, jg = tid & 3;
        int vg = v00 + v;
#pragma unroll
        for (int h = 0; h < 2; h++) {
            ushort8 val;
#pragma unroll
            for (int e = 0; e < 8; e++) {
                int j = jg * 16 + h * 8 + e;
                float f = (vg < V_CNT && j < J_CNT) ? lbs_weights[vg * J_CNT + j] : 0.0f;
                val[e] = f2bf(f);
            }
            int chunk = (jg * 2 + h) ^ (v & 7);
            *(ushort8*)(w_b + v * 128 + chunk * 16) = val;
        }
    }
    if (tid < 192) tr_s[tid] = transl[f0 * 3 + tid];

    const unsigned char* pfg = (const unsigned char*)pf_ext + (size_t)f0 * (KP * 2);
    const unsigned char* Bg  = (const unsigned char*)B_pack + (size_t)n0c * (KP * 2);

    // STAGE one 128B K-chunk (ks) into (pfd, Bd): 8 gload_lds per wave
#define STAGE_KS(ks, pfd, Bd)                                                              \
    {                                                                                      \
        const int kb = (ks) * 128;                                                         \
        _Pragma("unroll")                                                                  \
        for (int i = 0; i < 2; i++) {                                                      \
            int row0 = w * 16 + i * 8;                                                     \
            int row = row0 + (l >> 3);                                                     \
            const unsigned char* src = pfg + (size_t)row * (KP * 2) + kb +                 \
                                       (((l & 7) ^ (l >> 3)) * 16);                        \
            gl_lds16(src, (pfd) + row0 * 128);                                             \
        }                                                                                  \
        _Pragma("unroll")                                                                  \
        for (int i = 0; i < 6; i++) {                                                      \
            int row0 = i * 32 + w * 8;                                                     \
            int row = row0 + (l >> 3);                                                     \
            const unsigned char* src = Bg + (size_t)row * (KP * 2) + kb +                  \
                                       (((l & 7) ^ (l >> 3)) * 16);                        \
            gl_lds16(src, (Bd) + row0 * 128);                                              \
        }                                                                                  \
    }

    // -------- GEMM1: vp[f][n] = sum_k pf_ext[f][k] * B_pack[n][k] --------
    f32x4 acc[2][6];
#pragma unroll
    for (int m = 0; m < 2; m++)
#pragma unroll
        for (int nn = 0; nn < 6; nn++) acc[m][nn] = (f32x4){0.f, 0.f, 0.f, 0.f};

    // prologue: stage ks=0 into buf0; drain (also drains the w_b staging loads); barrier
    STAGE_KS(0, pf_b0, B_b0);
    asm volatile("s_waitcnt vmcnt(0)" ::: "memory");
    __builtin_amdgcn_s_barrier();

#pragma unroll
    for (int ks = 0; ks < 8; ks++) {
        unsigned char* pfc = (ks & 1) ? pf_b1 : pf_b0;
        unsigned char* Bc  = (ks & 1) ? B_b1 : B_b0;
        if (ks < 7) {
            unsigned char* pfn = (ks & 1) ? pf_b0 : pf_b1;
            unsigned char* Bn  = (ks & 1) ? B_b0 : B_b1;
            STAGE_KS(ks + 1, pfn, Bn);     // issue next tile; latency hides under compute
        }
#pragma unroll
        for (int ksub = 0; ksub < 2; ksub++) {
            bf16x8 a[2], b[6];
#pragma unroll
            for (int m = 0; m < 2; m++) {
                int f = wm * 32 + m * 16 + (l & 15);
                int off = f * 128 + ((ksub * 64 + (l >> 4) * 16) ^ ((f & 7) << 4));
                a[m] = *(const bf16x8*)(pfc + off);
            }
#pragma unroll
            for (int nn = 0; nn < 6; nn++) {
                int col = wn * 96 + nn * 16 + (l & 15);
                int off = col * 128 + ((ksub * 64 + (l >> 4) * 16) ^ ((col & 7) << 4));
                b[nn] = *(const bf16x8*)(Bc + off);
            }
#pragma unroll
            for (int m = 0; m < 2; m++)
#pragma unroll
                for (int nn = 0; nn < 6; nn++)
                    acc[m][nn] = __builtin_amdgcn_mfma_f32_16x16x32_bf16(a[m], b[nn], acc[m][nn], 0, 0, 0);
        }
        // next tile's loads drained AFTER this tile's compute; one barrier per K-step
        asm volatile("s_waitcnt vmcnt(0)" ::: "memory");
        __builtin_amdgcn_s_barrier();
    }
#undef STAGE_KS

    // write vp to LDS as bf16 [64f][196]  (overlays B_b[0]; all GEMM1 reads done at barrier)
#pragma unroll
    for (int m = 0; m < 2; m++)
#pragma unroll
        for (int nn = 0; nn < 6; nn++)
#pragma unroll
            for (int e = 0; e < 4; e++) {
                int f = wm * 32 + m * 16 + (l >> 4) * 4 + e;
                int col = wn * 96 + nn * 16 + (l & 15);
                vp_s[f * 196 + col] = f2bf(acc[m][nn][e]);
            }
    __syncthreads();

    // -------- GEMM2 per coord c: T[f][v][c*4+rr] = sum_j A_bf[f][c*4+rr][j] * w[v][j] ------
    const unsigned char* Ab = (const unsigned char*)A_bf;
    float res[3][8][2];
#pragma unroll
    for (int c = 0; c < 3; c++) {
        f32x4 acc2[8][2];
#pragma unroll
        for (int m = 0; m < 8; m++)
#pragma unroll
            for (int nn = 0; nn < 2; nn++) acc2[m][nn] = (f32x4){0.f, 0.f, 0.f, 0.f};
#pragma unroll
        for (int ksub = 0; ksub < 2; ksub++) {
            bf16x8 bw[2];
#pragma unroll
            for (int nn = 0; nn < 2; nn++) {
                int v = wn * 32 + nn * 16 + (l & 15);
                int off = v * 128 + ((ksub * 64 + (l >> 4) * 16) ^ ((v & 7) << 4));
                bw[nn] = *(const bf16x8*)(w_b + off);
            }
#pragma unroll
            for (int m = 0; m < 8; m++) {
                int row16 = l & 15;
                int f_rel = m * 4 + (row16 >> 2);
                int rr = row16 & 3;
                const unsigned char* asrc = Ab +
                    ((size_t)((f0 + wm * 32 + f_rel) * 12 + c * 4 + rr)) * 128 +
                    ksub * 64 + (l >> 4) * 16;
                bf16x8 af = *(const bf16x8*)asrc;
                acc2[m][0] = __builtin_amdgcn_mfma_f32_16x16x32_bf16(af, bw[0], acc2[m][0], 0, 0, 0);
                acc2[m][1] = __builtin_amdgcn_mfma_f32_16x16x32_bf16(af, bw[1], acc2[m][1], 0, 0, 0);
            }
        }
#pragma unroll
        for (int m = 0; m < 8; m++)
#pragma unroll
            for (int nn = 0; nn < 2; nn++) {
                int f_rel = wm * 32 + m * 4 + (l >> 4);      // frame within block
                int vloc = wn * 32 + nn * 16 + (l & 15);     // vertex within block
                float d0 = bf2f(vp_s[f_rel * 196 + vloc * 3 + 0]);
                float d1 = bf2f(vp_s[f_rel * 196 + vloc * 3 + 1]);
                float d2 = bf2f(vp_s[f_rel * 196 + vloc * 3 + 2]);
                f32x4 tt = acc2[m][nn];
                res[c][m][nn] = tt[0] * d0 + tt[1] * d1 + tt[2] * d2 + tt[3] + tr_s[f_rel * 3 + c];
            }
    }

    // -------- dense epilogue: restage res through LDS, write lane-consecutive dwords ------
    const int olim = N3 - v00 * 3;   // valid dwords within a 192-dword row (tail block)
#pragma unroll
    for (int chunk = 0; chunk < 2; chunk++) {
        __syncthreads();   // prior smem readers / prior copy done
        if (wm == chunk) {
#pragma unroll
            for (int m = 0; m < 8; m++)
#pragma unroll
                for (int nn = 0; nn < 2; nn++) {
                    int r = m * 4 + (l >> 4);
                    int colv = (wn * 32 + nn * 16 + (l & 15)) * 3;
#pragma unroll
                    for (int c = 0; c < 3; c++)
                        rst[r * 200 + colv + c] = res[c][m][nn];
                }
        }
        __syncthreads();
        size_t base = ((size_t)(f0 + chunk * 32) * V_CNT + v00) * 3;
#pragma unroll
        for (int k = 0; k < 24; k++) {
            int i = tid + k * 256;
            int r = i / 192;
            int o = i - r * 192;
            if (o < olim)
                out[base + (size_t)r * N3 + o] = rst[r * 200 + o];
        }
    }
}

extern "C" void kernel_launch(void* const* d_in, const int* in_sizes, int n_in,
                              void* d_out, int out_size, void* d_ws, size_t ws_size,
                              hipStream_t stream)
{
    const float* body_pose     = (const float*)d_in[0];
    const float* betas         = (const float*)d_in[1];
    const float* global_orient = (const float*)d_in[2];
    const float* transl        = (const float*)d_in[3];
    const float* v_template    = (const float*)d_in[4];
    const float* shapedirs     = (const float*)d_in[5];
    const float* posedirs      = (const float*)d_in[6];
    const float* lbs_weights   = (const float*)d_in[7];
    const float* J_template    = (const float*)d_in[8];
    const float* J_shapedirs   = (const float*)d_in[9];
    const float* odp           = (const float*)d_in[10];
    float* out = (float*)d_out;

    // ws layout: B_pack 31488*512*2 = 32,243,712 | pf_ext 512*512*2 | A_bf 512*12*64*2
    unsigned short* B_pack = (unsigned short*)d_ws;
    unsigned short* pf_ext = (unsigned short*)((char*)d_ws + 32243712);
    unsigned short* A_bf   = (unsigned short*)((char*)d_ws + 32243712 + 524288);

    dim3 rgrid(NPAD / 64, KP / 64);
    repack_kernel<<<rgrid, 256, 0, stream>>>(posedirs, shapedirs, v_template, B_pack);

    skel_kernel<<<NFRAMES, 64, 0, stream>>>(body_pose, betas, global_orient,
                                            J_template, J_shapedirs, odp,
                                            pf_ext, A_bf);

    gemm_kernel<<<VTILES * FTILES, 256, 0, stream>>>(pf_ext, B_pack, A_bf, lbs_weights,
                                                     transl, out);
}

// Round 11
// 116.325 us; speedup vs baseline: 1.7827x; 1.0234x over previous
//
#include <hip/hip_runtime.h>

#define V_CNT   10475
#define N3      31425      // V*3
#define NPAD    31488      // 164*192
#define J_CNT   55
#define NBETA   10
#define KP      512        // padded K for GEMM1 (486 pf + 10 betas + 1 vt + pad)
#define NFRAMES 512
#define BM      64         // frames per block
#define BNC     192        // columns (verts*3) per block
#define VTILES  164
#define FTILES  8

typedef __attribute__((ext_vector_type(8))) __bf16 bf16x8;
typedef __attribute__((ext_vector_type(8))) unsigned short ushort8;
typedef __attribute__((ext_vector_type(4))) float f32x4;

__device__ __forceinline__ unsigned short f2bf(float f) {
    unsigned u = __float_as_uint(f);
    u += 0x7fff + ((u >> 16) & 1);
    return (unsigned short)(u >> 16);
}
__device__ __forceinline__ float bf2f(unsigned short s) {
    return __uint_as_float(((unsigned)s) << 16);
}
// global -> LDS direct 16B load. LDS dest must be wave-uniform; lane writes base+lane*16.
__device__ __forceinline__ void gl_lds16(const void* g, void* l) {
    auto gp = (const __attribute__((address_space(1))) unsigned int*)(uintptr_t)g;
    auto lp = (__attribute__((address_space(3))) unsigned int*)(unsigned int)(uintptr_t)l;
    __builtin_amdgcn_global_load_lds(gp, lp, 16, 0, 0);
}

__device__ __constant__ int c_parents[J_CNT] = {
    -1, 0, 0, 0, 1, 2, 3, 4, 5, 6, 7, 8, 9, 9, 9, 12, 13, 14, 16, 17, 18, 19,
    15, 15, 15,
    20, 25, 26, 20, 28, 29, 20, 31, 32, 20, 34, 35, 20, 37, 38,
    21, 40, 41, 21, 43, 44, 21, 46, 47, 21, 49, 50, 21, 52, 53};

// ---------------- skeleton: rotmats, kinematic chain, pf_ext(bf16), A_bf(bf16) ------------
__global__ __launch_bounds__(64) void skel_kernel(
    const float* __restrict__ body_pose, const float* __restrict__ betas,
    const float* __restrict__ global_orient, const float* __restrict__ J_template,
    const float* __restrict__ J_shapedirs, const float* __restrict__ odp,
    unsigned short* __restrict__ pf_ext, unsigned short* __restrict__ A_bf)
{
    const int n = blockIdx.x;
    const int lane = threadIdx.x;
    __shared__ float R_s[J_CNT][9];
    __shared__ float j_s[J_CNT][3];
    __shared__ float G_s[J_CNT][12];

    if (lane < J_CNT) {
        float aa0, aa1, aa2;
        if (lane == 0) {
            aa0 = global_orient[n * 3 + 0];
            aa1 = global_orient[n * 3 + 1];
            aa2 = global_orient[n * 3 + 2];
        } else if (lane < 22) {
            int o = n * 63 + (lane - 1) * 3;
            aa0 = body_pose[o]; aa1 = body_pose[o + 1]; aa2 = body_pose[o + 2];
        } else {
            int o = (lane - 22) * 3;
            aa0 = odp[o]; aa1 = odp[o + 1]; aa2 = odp[o + 2];
        }
        float ang = sqrtf(aa0 * aa0 + aa1 * aa1 + aa2 * aa2 + 1e-12f);
        float inv = 1.0f / ang;
        float ax = aa0 * inv, ay = aa1 * inv, az = aa2 * inv;
        float s = sinf(ang), c = cosf(ang), cc = 1.0f - c;
        float R[9];
        R[0] = c + cc * ax * ax;        R[1] = -s * az + cc * ax * ay;  R[2] = s * ay + cc * ax * az;
        R[3] = s * az + cc * ax * ay;   R[4] = c + cc * ay * ay;        R[5] = -s * ax + cc * ay * az;
        R[6] = -s * ay + cc * ax * az;  R[7] = s * ax + cc * ay * az;   R[8] = c + cc * az * az;
#pragma unroll
        for (int k = 0; k < 9; k++) R_s[lane][k] = R[k];
#pragma unroll
        for (int cd = 0; cd < 3; cd++) {
            float acc = J_template[lane * 3 + cd];
#pragma unroll
            for (int k = 0; k < NBETA; k++)
                acc += betas[n * NBETA + k] * J_shapedirs[(lane * 3 + cd) * NBETA + k];
            j_s[lane][cd] = acc;
        }
        if (lane >= 1) {
#pragma unroll
            for (int e = 0; e < 9; e++)
                pf_ext[n * KP + (lane - 1) * 9 + e] =
                    f2bf(R[e] - ((e == 0 || e == 4 || e == 8) ? 1.0f : 0.0f));
        }
    }
    if (lane == 55) {
#pragma unroll
        for (int b = 0; b < NBETA; b++) pf_ext[n * KP + 486 + b] = f2bf(betas[n * NBETA + b]);
        pf_ext[n * KP + 496] = 0x3F80;  // 1.0 bf16 (multiplies v_template row)
    }
    if (lane == 56) {
        for (int k = 497; k < KP; k++) pf_ext[n * KP + k] = 0;
    }
    __syncthreads();
    if (lane == 0) {
        for (int r = 0; r < 3; r++) {
            G_s[0][r * 4 + 0] = R_s[0][r * 3 + 0];
            G_s[0][r * 4 + 1] = R_s[0][r * 3 + 1];
            G_s[0][r * 4 + 2] = R_s[0][r * 3 + 2];
            G_s[0][r * 4 + 3] = j_s[0][r];
        }
        for (int i = 1; i < J_CNT; i++) {
            int p = c_parents[i];
            float rel0 = j_s[i][0] - j_s[p][0];
            float rel1 = j_s[i][1] - j_s[p][1];
            float rel2 = j_s[i][2] - j_s[p][2];
            for (int r = 0; r < 3; r++) {
                float g0 = G_s[p][r * 4 + 0], g1 = G_s[p][r * 4 + 1], g2 = G_s[p][r * 4 + 2];
                G_s[i][r * 4 + 0] = g0 * R_s[i][0] + g1 * R_s[i][3] + g2 * R_s[i][6];
                G_s[i][r * 4 + 1] = g0 * R_s[i][1] + g1 * R_s[i][4] + g2 * R_s[i][7];
                G_s[i][r * 4 + 2] = g0 * R_s[i][2] + g1 * R_s[i][5] + g2 * R_s[i][8];
                G_s[i][r * 4 + 3] = g0 * rel0 + g1 * rel1 + g2 * rel2 + G_s[p][r * 4 + 3];
            }
        }
    }
    __syncthreads();
    // A_bf[f][12][64]: row r = c*4+d of the 3x4 A matrix, K-dim = joint (padded to 64)
    float vals[12];
#pragma unroll
    for (int r = 0; r < 12; r++) vals[r] = 0.0f;
    if (lane < J_CNT) {
        const float jx = j_s[lane][0], jy = j_s[lane][1], jz = j_s[lane][2];
#pragma unroll
        for (int r = 0; r < 3; r++) {
            float g0 = G_s[lane][r * 4 + 0], g1 = G_s[lane][r * 4 + 1], g2 = G_s[lane][r * 4 + 2];
            vals[r * 4 + 0] = g0;
            vals[r * 4 + 1] = g1;
            vals[r * 4 + 2] = g2;
            vals[r * 4 + 3] = G_s[lane][r * 4 + 3] - (g0 * jx + g1 * jy + g2 * jz);
        }
    }
#pragma unroll
    for (int r = 0; r < 12; r++)
        A_bf[(n * 12 + r) * 64 + lane] = f2bf(vals[r]);
}

// ---------------- repack: B_pack[n][k] bf16 (transpose of posedirs, + shapedirs + v_template) ---
__global__ __launch_bounds__(256) void repack_kernel(
    const float* __restrict__ posedirs, const float* __restrict__ shapedirs,
    const float* __restrict__ v_template, unsigned short* __restrict__ B_pack)
{
    __shared__ float t[64][65];
    const int n0 = blockIdx.x * 64, k0 = blockIdx.y * 64;
    const int tn = threadIdx.x & 63, tk4 = threadIdx.x >> 6;
#pragma unroll
    for (int rep = 0; rep < 16; rep++) {
        int kl = rep * 4 + tk4;
        int kg = k0 + kl, ng = n0 + tn;
        float v = 0.0f;
        if (ng < N3) {
            if (kg < 486)       v = posedirs[(size_t)kg * N3 + ng];
            else if (kg < 496)  v = shapedirs[ng * NBETA + (kg - 486)];
            else if (kg == 496) v = v_template[ng];
        }
        t[kl][tn] = v;
    }
    __syncthreads();
    // store side: lane handles (n_local, kgroup of 8) -> one ushort8 (16B) store
#pragma unroll
    for (int rep = 0; rep < 2; rep++) {
        int nl = rep * 32 + (threadIdx.x >> 3);
        int kg = threadIdx.x & 7;
        ushort8 val;
#pragma unroll
        for (int j = 0; j < 8; j++) val[j] = f2bf(t[kg * 8 + j][nl]);
        *(ushort8*)(&B_pack[(size_t)(n0 + nl) * KP + k0 + kg * 8]) = val;
    }
}

// ---------------- fused GEMM: vposed (MFMA, counted-vmcnt dbuf pipeline) -> skinning -------
// R10 structure (XCD co-location swizzle) + T4 counted vmcnt: per K-step wait only for the
// PREVIOUS step's 8 staging loads (vmcnt(8)); the just-issued 8 stay in flight across the
// barrier. Drain-to-0 per step was the serializer (m218: counted-vs-drain0 = +38-73%).
__global__ __launch_bounds__(256, 2) void gemm_kernel(
    const unsigned short* __restrict__ pf_ext, const unsigned short* __restrict__ B_pack,
    const unsigned short* __restrict__ A_bf, const float* __restrict__ lbs_weights,
    const float* __restrict__ transl, float* __restrict__ out)
{
    // LDS map (74496 B total -> 2 blocks/CU):
    //   0     pf_b[0] 8192      [64f][128B] swizzled
    //   8192  pf_b[1] 8192
    //   16384 B_b[0] 24576      [192n][128B] swizzled
    //   40960 B_b[1] 24576
    //   65536 w_b    8192       [64v][128B] swizzled
    //   73728 tr_s   768
    // overlays (after GEMM1 completes):
    //   vp_s  = smem+16384, [64f][196] ushort
    //   rst   = smem+41472, [32][200] float
    __shared__ __align__(128) unsigned char smem[74496];
    unsigned char* pf_b0 = smem;
    unsigned char* pf_b1 = smem + 8192;
    unsigned char* B_b0  = smem + 16384;
    unsigned char* B_b1  = smem + 40960;
    unsigned char* w_b   = smem + 65536;
    float* tr_s          = (float*)(smem + 73728);
    unsigned short* vp_s = (unsigned short*)(smem + 16384);
    float* rst           = (float*)(smem + 41472);

    const int tid = threadIdx.x;
    const int w = tid >> 6, l = tid & 63;
    const int wm = w >> 1, wn = w & 1;         // wave tile: frames wm*32.., cols wn*96..

    // ---- XCD co-location decode: 64-block groups = 8 vtiles x 8 ftiles; within a group
    // vtile = gi&7 = bid%8 -> XCD (round-robin), so a vtile's 8 ftile-blocks share an XCD.
    const int bid = blockIdx.x;
    const int group = bid >> 6, gi = bid & 63;
    int vt, ft;
    if (group < 20) { vt = group * 8 + (gi & 7); ft = gi >> 3; }
    else            { vt = 160 + (gi & 3);       ft = gi >> 2; }   // tail: 4 vtiles
    const int f0 = ft * BM;
    const int v00 = vt * 64;
    const int n0c = vt * BNC;

    // stage lbs weights tile -> w_b [64v][64j] bf16, XOR-swizzled chunks
    {
        int v = tid >> 2, jg = tid & 3;
        int vg = v00 + v;
#pragma unroll
        for (int h = 0; h < 2; h++) {
            ushort8 val;
#pragma unroll
            for (int e = 0; e < 8; e++) {
                int j = jg * 16 + h * 8 + e;
                float f = (vg < V_CNT && j < J_CNT) ? lbs_weights[vg * J_CNT + j] : 0.0f;
                val[e] = f2bf(f);
            }
            int chunk = (jg * 2 + h) ^ (v & 7);
            *(ushort8*)(w_b + v * 128 + chunk * 16) = val;
        }
    }
    if (tid < 192) tr_s[tid] = transl[f0 * 3 + tid];

    const unsigned char* pfg = (const unsigned char*)pf_ext + (size_t)f0 * (KP * 2);
    const unsigned char* Bg  = (const unsigned char*)B_pack + (size_t)n0c * (KP * 2);

    // STAGE one 128B K-chunk (ks) into (pfd, Bd): 8 gload_lds per wave
#define STAGE_KS(ks, pfd, Bd)                                                              \
    {                                                                                      \
        const int kb = (ks) * 128;                                                         \
        _Pragma("unroll")                                                                  \
        for (int i = 0; i < 2; i++) {                                                      \
            int row0 = w * 16 + i * 8;                                                     \
            int row = row0 + (l >> 3);                                                     \
            const unsigned char* src = pfg + (size_t)row * (KP * 2) + kb +                 \
                                       (((l & 7) ^ (l >> 3)) * 16);                        \
            gl_lds16(src, (pfd) + row0 * 128);                                             \
        }                                                                                  \
        _Pragma("unroll")                                                                  \
        for (int i = 0; i < 6; i++) {                                                      \
            int row0 = i * 32 + w * 8;                                                     \
            int row = row0 + (l >> 3);                                                     \
            const unsigned char* src = Bg + (size_t)row * (KP * 2) + kb +                  \
                                       (((l & 7) ^ (l >> 3)) * 16);                        \
            gl_lds16(src, (Bd) + row0 * 128);                                              \
        }                                                                                  \
    }

    // -------- GEMM1: vp[f][n] = sum_k pf_ext[f][k] * B_pack[n][k] --------
    f32x4 acc[2][6];
#pragma unroll
    for (int m = 0; m < 2; m++)
#pragma unroll
        for (int nn = 0; nn < 6; nn++) acc[m][nn] = (f32x4){0.f, 0.f, 0.f, 0.f};

    // prologue: stage ks=0 AND ks=1 (16 loads/wave in flight); wait only for ks=0's 8.
    STAGE_KS(0, pf_b0, B_b0);
    STAGE_KS(1, pf_b1, B_b1);
    asm volatile("s_waitcnt vmcnt(8)" ::: "memory");
    __builtin_amdgcn_sched_barrier(0);
    __builtin_amdgcn_s_barrier();

#pragma unroll
    for (int ks = 0; ks < 8; ks++) {
        unsigned char* pfc = (ks & 1) ? pf_b1 : pf_b0;
        unsigned char* Bc  = (ks & 1) ? B_b1 : B_b0;
        // compute(ks) from buf[ks&1]
#pragma unroll
        for (int ksub = 0; ksub < 2; ksub++) {
            bf16x8 a[2], b[6];
#pragma unroll
            for (int m = 0; m < 2; m++) {
                int f = wm * 32 + m * 16 + (l & 15);
                int off = f * 128 + ((ksub * 64 + (l >> 4) * 16) ^ ((f & 7) << 4));
                a[m] = *(const bf16x8*)(pfc + off);
            }
#pragma unroll
            for (int nn = 0; nn < 6; nn++) {
                int col = wn * 96 + nn * 16 + (l & 15);
                int off = col * 128 + ((ksub * 64 + (l >> 4) * 16) ^ ((col & 7) << 4));
                b[nn] = *(const bf16x8*)(Bc + off);
            }
#pragma unroll
            for (int m = 0; m < 2; m++)
#pragma unroll
                for (int nn = 0; nn < 6; nn++)
                    acc[m][nn] = __builtin_amdgcn_mfma_f32_16x16x32_bf16(a[m], b[nn], acc[m][nn], 0, 0, 0);
        }
        // all waves done reading buf[ks&1] before it is re-staged
        __builtin_amdgcn_sched_barrier(0);
        __builtin_amdgcn_s_barrier();
        if (ks < 6) {
            STAGE_KS(ks + 2, pfc, Bc);     // overwrite the buffer just consumed
        }
        if (ks < 7) {
            // wait for ks+1's loads (issued a full step ago); ks+2's 8 stay in flight
            if (ks < 6) asm volatile("s_waitcnt vmcnt(8)" ::: "memory");
            else        asm volatile("s_waitcnt vmcnt(0)" ::: "memory");
            __builtin_amdgcn_sched_barrier(0);
            __builtin_amdgcn_s_barrier();
        }
    }
#undef STAGE_KS

    // write vp to LDS as bf16 [64f][196]  (overlays B_b[0]; last B_b0 read was compute(6),
    // and the post-compute(7) barrier above orders all waves before these writes)
#pragma unroll
    for (int m = 0; m < 2; m++)
#pragma unroll
        for (int nn = 0; nn < 6; nn++)
#pragma unroll
            for (int e = 0; e < 4; e++) {
                int f = wm * 32 + m * 16 + (l >> 4) * 4 + e;
                int col = wn * 96 + nn * 16 + (l & 15);
                vp_s[f * 196 + col] = f2bf(acc[m][nn][e]);
            }
    __syncthreads();

    // -------- GEMM2 per coord c: T[f][v][c*4+rr] = sum_j A_bf[f][c*4+rr][j] * w[v][j] ------
    const unsigned char* Ab = (const unsigned char*)A_bf;
    float res[3][8][2];
#pragma unroll
    for (int c = 0; c < 3; c++) {
        f32x4 acc2[8][2];
#pragma unroll
        for (int m = 0; m < 8; m++)
#pragma unroll
            for (int nn = 0; nn < 2; nn++) acc2[m][nn] = (f32x4){0.f, 0.f, 0.f, 0.f};
#pragma unroll
        for (int ksub = 0; ksub < 2; ksub++) {
            bf16x8 bw[2];
#pragma unroll
            for (int nn = 0; nn < 2; nn++) {
                int v = wn * 32 + nn * 16 + (l & 15);
                int off = v * 128 + ((ksub * 64 + (l >> 4) * 16) ^ ((v & 7) << 4));
                bw[nn] = *(const bf16x8*)(w_b + off);
            }
#pragma unroll
            for (int m = 0; m < 8; m++) {
                int row16 = l & 15;
                int f_rel = m * 4 + (row16 >> 2);
                int rr = row16 & 3;
                const unsigned char* asrc = Ab +
                    ((size_t)((f0 + wm * 32 + f_rel) * 12 + c * 4 + rr)) * 128 +
                    ksub * 64 + (l >> 4) * 16;
                bf16x8 af = *(const bf16x8*)asrc;
                acc2[m][0] = __builtin_amdgcn_mfma_f32_16x16x32_bf16(af, bw[0], acc2[m][0], 0, 0, 0);
                acc2[m][1] = __builtin_amdgcn_mfma_f32_16x16x32_bf16(af, bw[1], acc2[m][1], 0, 0, 0);
            }
        }
#pragma unroll
        for (int m = 0; m < 8; m++)
#pragma unroll
            for (int nn = 0; nn < 2; nn++) {
                int f_rel = wm * 32 + m * 4 + (l >> 4);      // frame within block
                int vloc = wn * 32 + nn * 16 + (l & 15);     // vertex within block
                float d0 = bf2f(vp_s[f_rel * 196 + vloc * 3 + 0]);
                float d1 = bf2f(vp_s[f_rel * 196 + vloc * 3 + 1]);
                float d2 = bf2f(vp_s[f_rel * 196 + vloc * 3 + 2]);
                f32x4 tt = acc2[m][nn];
                res[c][m][nn] = tt[0] * d0 + tt[1] * d1 + tt[2] * d2 + tt[3] + tr_s[f_rel * 3 + c];
            }
    }

    // -------- dense epilogue: restage res through LDS, write lane-consecutive dwords ------
    const int olim = N3 - v00 * 3;   // valid dwords within a 192-dword row (tail block)
#pragma unroll
    for (int chunk = 0; chunk < 2; chunk++) {
        __syncthreads();   // prior smem readers / prior copy done
        if (wm == chunk) {
#pragma unroll
            for (int m = 0; m < 8; m++)
#pragma unroll
                for (int nn = 0; nn < 2; nn++) {
                    int r = m * 4 + (l >> 4);
                    int colv = (wn * 32 + nn * 16 + (l & 15)) * 3;
#pragma unroll
                    for (int c = 0; c < 3; c++)
                        rst[r * 200 + colv + c] = res[c][m][nn];
                }
        }
        __syncthreads();
        size_t base = ((size_t)(f0 + chunk * 32) * V_CNT + v00) * 3;
#pragma unroll
        for (int k = 0; k < 24; k++) {
            int i = tid + k * 256;
            int r = i / 192;
            int o = i - r * 192;
            if (o < olim)
                out[base + (size_t)r * N3 + o] = rst[r * 200 + o];
        }
    }
}

extern "C" void kernel_launch(void* const* d_in, const int* in_sizes, int n_in,
                              void* d_out, int out_size, void* d_ws, size_t ws_size,
                              hipStream_t stream)
{
    const float* body_pose     = (const float*)d_in[0];
    const float* betas         = (const float*)d_in[1];
    const float* global_orient = (const float*)d_in[2];
    const float* transl        = (const float*)d_in[3];
    const float* v_template    = (const float*)d_in[4];
    const float* shapedirs     = (const float*)d_in[5];
    const float* posedirs      = (const float*)d_in[6];
    const float* lbs_weights   = (const float*)d_in[7];
    const float* J_template    = (const float*)d_in[8];
    const float* J_shapedirs   = (const float*)d_in[9];
    const float* odp           = (const float*)d_in[10];
    float* out = (float*)d_out;

    // ws layout: B_pack 31488*512*2 = 32,243,712 | pf_ext 512*512*2 | A_bf 512*12*64*2
    unsigned short* B_pack = (unsigned short*)d_ws;
    unsigned short* pf_ext = (unsigned short*)((char*)d_ws + 32243712);
    unsigned short* A_bf   = (unsigned short*)((char*)d_ws + 32243712 + 524288);

    dim3 rgrid(NPAD / 64, KP / 64);
    repack_kernel<<<rgrid, 256, 0, stream>>>(posedirs, shapedirs, v_template, B_pack);

    skel_kernel<<<NFRAMES, 64, 0, stream>>>(body_pose, betas, global_orient,
                                            J_template, J_shapedirs, odp,
                                            pf_ext, A_bf);

    gemm_kernel<<<VTILES * FTILES, 256, 0, stream>>>(pf_ext, B_pack, A_bf, lbs_weights,
                                                     transl, out);
}